// Round 1
// baseline (82.202 us; speedup 1.0000x reference)
//
#include <hip/hip_runtime.h>
#include <stdint.h>

// JAX RNG variant: 1 = jax_threefry_partitionable=True (modern default),
//                  0 = legacy original counter layout. Flip if absmax ~O(1).
#define PARTITIONABLE 1

#define B 4096
#define D 512

__host__ __device__ __forceinline__ uint32_t rotl32(uint32_t x, int d) {
    return (x << d) | (x >> (32 - d));
}

// Threefry-2x32, 20 rounds — bit-exact match of jax._src.prng.threefry2x32.
__host__ __device__ __forceinline__ void tf2x32(uint32_t k0, uint32_t k1,
                                                uint32_t x0, uint32_t x1,
                                                uint32_t& o0, uint32_t& o1) {
    const uint32_t k2 = k0 ^ k1 ^ 0x1BD11BDAu;
#define TF_ROUND(r) { x0 += x1; x1 = rotl32(x1, r); x1 ^= x0; }
    x0 += k0; x1 += k1;
    TF_ROUND(13) TF_ROUND(15) TF_ROUND(26) TF_ROUND(6)
    x0 += k1; x1 += k2 + 1u;
    TF_ROUND(17) TF_ROUND(29) TF_ROUND(16) TF_ROUND(24)
    x0 += k2; x1 += k0 + 2u;
    TF_ROUND(13) TF_ROUND(15) TF_ROUND(26) TF_ROUND(6)
    x0 += k0; x1 += k1 + 3u;
    TF_ROUND(17) TF_ROUND(29) TF_ROUND(16) TF_ROUND(24)
    x0 += k1; x1 += k2 + 4u;
    TF_ROUND(13) TF_ROUND(15) TF_ROUND(26) TF_ROUND(6)
    x0 += k2; x1 += k0 + 5u;
#undef TF_ROUND
    o0 = x0; o1 = x1;
}

__device__ __forceinline__ unsigned long long umax64(unsigned long long a,
                                                     unsigned long long b) {
    return a > b ? a : b;
}

// ---------------- Kernel A: sq[r] = ||E[r]||^2 ----------------
__global__ __launch_bounds__(64) void sq_kernel(const float* __restrict__ E,
                                                float* __restrict__ sq) {
    const int r = blockIdx.x;
    const int lane = threadIdx.x;
    const float4* er = (const float4*)(E + (size_t)r * D);
    float s = 0.f;
#pragma unroll
    for (int j = 0; j < 2; ++j) {
        float4 a = er[lane * 2 + j];
        s += a.x * a.x + a.y * a.y + a.z * a.z + a.w * a.w;
    }
#pragma unroll
    for (int off = 32; off > 0; off >>= 1) s += __shfl_down(s, off);
    if (lane == 0) sq[r] = s;
}

// ---------------- Kernel B: per-row masked argmax of JAX uniforms ----------
// Reproduces argmax(where(mask, u, -1), axis=1) with first-index tie-break.
// u is monotone in (bits >> 9), so compare packed (bits>>9, ~col) as u64.
__global__ __launch_bounds__(256) void select_kernel(
        const int* __restrict__ labels, int* __restrict__ idxp,
        int* __restrict__ idxn, uint32_t kp0, uint32_t kp1, uint32_t kn0,
        uint32_t kn1) {
    __shared__ int slab[B];
    const int r = blockIdx.x;
    const int t = threadIdx.x;
    for (int j = t; j < B / 4; j += 256)
        ((int4*)slab)[j] = ((const int4*)labels)[j];
    __syncthreads();
    const int labr = slab[r];

    unsigned long long bestp = 0ull, bestn = 0ull;
#pragma unroll
    for (int j = 0; j < B / 256; ++j) {
        const int c = t + j * 256;
        const uint32_t flat = ((uint32_t)r << 12) + (uint32_t)c;
        uint32_t bitsp, bitsn, o0, o1;
#if PARTITIONABLE
        tf2x32(kp0, kp1, 0u, flat, o0, o1); bitsp = o0 ^ o1;
        tf2x32(kn0, kn1, 0u, flat, o0, o1); bitsn = o0 ^ o1;
#else
        const uint32_t H = 1u << 23;
        const uint32_t x0 = (flat < H) ? flat : flat - H;
        const uint32_t x1 = x0 + H;
        tf2x32(kp0, kp1, x0, x1, o0, o1); bitsp = (flat < H) ? o0 : o1;
        tf2x32(kn0, kn1, x0, x1, o0, o1); bitsn = (flat < H) ? o0 : o1;
#endif
        const int labc = slab[c];
        const bool same = (labc == labr);
        const unsigned long long packp =
            ((unsigned long long)(bitsp >> 9) << 32) |
            (unsigned long long)(0xFFFFFFFFu - (uint32_t)c);
        const unsigned long long packn =
            ((unsigned long long)(bitsn >> 9) << 32) |
            (unsigned long long)(0xFFFFFFFFu - (uint32_t)c);
        if (same && c != r) bestp = umax64(bestp, packp);
        if (!same) bestn = umax64(bestn, packn);
    }
    // wave reduce (64 lanes)
#pragma unroll
    for (int off = 32; off > 0; off >>= 1) {
        bestp = umax64(bestp, __shfl_down(bestp, off));
        bestn = umax64(bestn, __shfl_down(bestn, off));
    }
    __shared__ unsigned long long redp[4], redn[4];
    if ((t & 63) == 0) { redp[t >> 6] = bestp; redn[t >> 6] = bestn; }
    __syncthreads();
    if (t == 0) {
#pragma unroll
        for (int k = 1; k < 4; ++k) {
            bestp = umax64(bestp, redp[k]);
            bestn = umax64(bestn, redn[k]);
        }
        idxp[r] = bestp ? (int)(0xFFFFFFFFu - (uint32_t)bestp) : -1;
        idxn[r] = bestn ? (int)(0xFFFFFFFFu - (uint32_t)bestn) : -1;
    }
}

// ---------------- Kernel C: per-row triplet loss ----------------
__global__ __launch_bounds__(64) void loss_kernel(
        const float* __restrict__ E, const float* __restrict__ sq,
        const int* __restrict__ idxp, const int* __restrict__ idxn,
        float* __restrict__ tl) {
    const int r = blockIdx.x;
    const int lane = threadIdx.x;
    const int ip = idxp[r];
    const int in_ = idxn[r];
    const float4* er = (const float4*)(E + (size_t)r * D);
    float dp = 0.f, dn = 0.f;
    if (ip >= 0) {
        const float4* ep = (const float4*)(E + (size_t)ip * D);
#pragma unroll
        for (int j = 0; j < 2; ++j) {
            float4 a = er[lane * 2 + j];
            float4 b = ep[lane * 2 + j];
            dp += a.x * b.x + a.y * b.y + a.z * b.z + a.w * b.w;
        }
    }
    if (in_ >= 0) {
        const float4* en = (const float4*)(E + (size_t)in_ * D);
#pragma unroll
        for (int j = 0; j < 2; ++j) {
            float4 a = er[lane * 2 + j];
            float4 b = en[lane * 2 + j];
            dn += a.x * b.x + a.y * b.y + a.z * b.z + a.w * b.w;
        }
    }
#pragma unroll
    for (int off = 32; off > 0; off >>= 1) {
        dp += __shfl_down(dp, off);
        dn += __shfl_down(dn, off);
    }
    if (lane == 0) {
        const float pd = (ip >= 0) ? fmaxf(sq[r] + sq[ip] - 2.0f * dp, 0.f) : 0.f;
        const float nd = (in_ >= 0) ? fmaxf(sq[r] + sq[in_] - 2.0f * dn, 0.f) : 0.f;
        tl[r] = fmaxf(pd - nd + 1.0f, 0.f);
    }
}

// ---------------- Kernel D: deterministic final reduction ----------------
__global__ __launch_bounds__(256) void finalize_kernel(
        const float* __restrict__ tl, float* __restrict__ out) {
    const int t = threadIdx.x;
    float s = 0.f;
    int c = 0;
    for (int j = t; j < B; j += 256) {
        const float v = tl[j];
        s += v;
        if (v > 1e-16f) c++;
    }
#pragma unroll
    for (int off = 32; off > 0; off >>= 1) {
        s += __shfl_down(s, off);
        c += __shfl_down(c, off);
    }
    __shared__ float ss[4];
    __shared__ int sc[4];
    if ((t & 63) == 0) { ss[t >> 6] = s; sc[t >> 6] = c; }
    __syncthreads();
    if (t == 0) {
#pragma unroll
        for (int k = 1; k < 4; ++k) { s += ss[k]; c += sc[k]; }
        out[0] = (c == 0) ? 0.0f : s * (1.0f / 4096.0f);
    }
}

extern "C" void kernel_launch(void* const* d_in, const int* in_sizes, int n_in,
                              void* d_out, int out_size, void* d_ws,
                              size_t ws_size, hipStream_t stream) {
    const float* E = (const float*)d_in[0];
    const int* labels = (const int*)d_in[1];
    float* out = (float*)d_out;

    char* ws = (char*)d_ws;
    float* sq = (float*)(ws);                 // 16 KB
    int* idxp = (int*)(ws + 16384);           // 16 KB
    int* idxn = (int*)(ws + 32768);           // 16 KB
    float* tl = (float*)(ws + 49152);         // 16 KB

    // Host-side key derivation (pure CPU arithmetic; graph-capture safe).
    uint32_t kp0, kp1, kn0, kn1;
#if PARTITIONABLE
    // split = fold-like: key i = tf2x32(master, hi=0, lo=i)
    tf2x32(0u, 42u, 0u, 0u, kp0, kp1);
    tf2x32(0u, 42u, 0u, 1u, kn0, kn1);
#else
    // legacy split: counts iota(4) -> blocks (0,2),(1,3); kp=(a0,a1), kn=(b0,b1)
    uint32_t a0, b0, a1, b1;
    tf2x32(0u, 42u, 0u, 2u, a0, b0);
    tf2x32(0u, 42u, 1u, 3u, a1, b1);
    kp0 = a0; kp1 = a1; kn0 = b0; kn1 = b1;
#endif

    sq_kernel<<<B, 64, 0, stream>>>(E, sq);
    select_kernel<<<B, 256, 0, stream>>>(labels, idxp, idxn, kp0, kp1, kn0, kn1);
    loss_kernel<<<B, 64, 0, stream>>>(E, sq, idxp, idxn, tl);
    finalize_kernel<<<1, 256, 0, stream>>>(tl, out);
}

// Round 2
// 63.507 us; speedup vs baseline: 1.2944x; 1.2944x over previous
//
#include <hip/hip_runtime.h>
#include <stdint.h>

#define B 4096
#define D 512

// Grid layout of the fused select kernel (all blocks 256 threads):
//   [0, 4096)        : negative-selection, one block per row (16 cols/thread)
//   [4096, 5120)     : positive-selection, 4 rows per block (1 row per wave)
//   [5120, 5184)     : sq[r] = ||E[r]||^2, 64 rows per block (16 per wave)
#define NB_NEG 4096
#define NB_POS 1024
#define NB_SQ 64
#define NB_TOTAL (NB_NEG + NB_POS + NB_SQ)

__host__ __device__ __forceinline__ uint32_t rotl32(uint32_t x, int d) {
    return (x << d) | (x >> (32 - d));
}

// Threefry-2x32, 20 rounds — bit-exact match of jax._src.prng.threefry2x32.
__host__ __device__ __forceinline__ void tf2x32(uint32_t k0, uint32_t k1,
                                                uint32_t x0, uint32_t x1,
                                                uint32_t& o0, uint32_t& o1) {
    const uint32_t k2 = k0 ^ k1 ^ 0x1BD11BDAu;
#define TF_ROUND(r) { x0 += x1; x1 = rotl32(x1, r); x1 ^= x0; }
    x0 += k0; x1 += k1;
    TF_ROUND(13) TF_ROUND(15) TF_ROUND(26) TF_ROUND(6)
    x0 += k1; x1 += k2 + 1u;
    TF_ROUND(17) TF_ROUND(29) TF_ROUND(16) TF_ROUND(24)
    x0 += k2; x1 += k0 + 2u;
    TF_ROUND(13) TF_ROUND(15) TF_ROUND(26) TF_ROUND(6)
    x0 += k0; x1 += k1 + 3u;
    TF_ROUND(17) TF_ROUND(29) TF_ROUND(16) TF_ROUND(24)
    x0 += k1; x1 += k2 + 4u;
    TF_ROUND(13) TF_ROUND(15) TF_ROUND(26) TF_ROUND(6)
    x0 += k2; x1 += k0 + 5u;
#undef TF_ROUND
    o0 = x0; o1 = x1;
}

// JAX partitionable draw for uint32 element `flat`: counter (0, flat), fold.
__device__ __forceinline__ uint32_t draw32(uint32_t k0, uint32_t k1,
                                           uint32_t flat) {
    uint32_t o0, o1;
    tf2x32(k0, k1, 0u, flat, o0, o1);
    return o0 ^ o1;
}

__device__ __forceinline__ unsigned long long umax64(unsigned long long a,
                                                     unsigned long long b) {
    return a > b ? a : b;
}

// Pack (bestv, bestc) so that u64-max == (larger uniform, then smaller col).
// bestv in [0, 2^23); +1 so pack==0 <=> "no candidate".
__device__ __forceinline__ unsigned long long packbest(int bestv, int bestc) {
    return (bestv < 0)
               ? 0ull
               : ((((unsigned long long)(uint32_t)bestv + 1ull) << 12) |
                  (unsigned long long)(uint32_t)(4095 - bestc));
}

__global__ __launch_bounds__(256) void fused_select_kernel(
        const float* __restrict__ E, const int* __restrict__ labels,
        float* __restrict__ sq, int* __restrict__ idxp, int* __restrict__ idxn,
        uint32_t kp0, uint32_t kp1, uint32_t kn0, uint32_t kn1) {
    const int bid = blockIdx.x;
    const int t = threadIdx.x;
    const int lane = t & 63;
    const int w = t >> 6;

    if (bid < NB_NEG) {
        // ----- negative selection: row = bid, hash kn for ALL columns -----
        const int r = bid;
        const int labr = labels[r];
        int bestv = -1, bestc = 0;
#pragma unroll
        for (int j = 0; j < B / 256; ++j) {
            const int c = t + j * 256;
            const uint32_t bits = draw32(kn0, kn1, ((uint32_t)r << 12) + c);
            const int v = (int)(bits >> 9);
            const int labc = labels[c];
            if ((labc != labr) & (v > bestv)) { bestv = v; bestc = c; }
        }
        unsigned long long best = packbest(bestv, bestc);
#pragma unroll
        for (int off = 32; off > 0; off >>= 1)
            best = umax64(best, __shfl_down(best, off));
        __shared__ unsigned long long red[4];
        if (lane == 0) red[w] = best;
        __syncthreads();
        if (t == 0) {
#pragma unroll
            for (int k = 1; k < 4; ++k) best = umax64(best, red[k]);
            idxn[r] = best ? (int)(4095u - (uint32_t)(best & 0xFFFull)) : -1;
        }
    } else if (bid < NB_NEG + NB_POS) {
        // ----- positive selection: 1 row per wave, hash only same-label -----
        const int r = (bid - NB_NEG) * 4 + w;
        const int labr = labels[r];
        int bestv = -1, bestc = 0;
#pragma unroll 4
        for (int i = 0; i < B / 64; ++i) {
            const int c = i * 64 + lane;
            const int labc = labels[c];
            const bool cand = (labc == labr) && (c != r);
            if (__any(cand)) {
                const uint32_t bits =
                    draw32(kp0, kp1, ((uint32_t)r << 12) + c);
                const int v = (int)(bits >> 9);
                if (cand & (v > bestv)) { bestv = v; bestc = c; }
            }
        }
        unsigned long long best = packbest(bestv, bestc);
#pragma unroll
        for (int off = 32; off > 0; off >>= 1)
            best = umax64(best, __shfl_down(best, off));
        if (lane == 0)
            idxp[r] = best ? (int)(4095u - (uint32_t)(best & 0xFFFull)) : -1;
    } else {
        // ----- sq: 16 rows per wave -----
        const int base = (bid - NB_NEG - NB_POS) * 64 + w * 16;
#pragma unroll 2
        for (int k = 0; k < 16; ++k) {
            const int r = base + k;
            const float4* er = (const float4*)(E + (size_t)r * D);
            float4 a0 = er[lane * 2];
            float4 a1 = er[lane * 2 + 1];
            float s = a0.x * a0.x + a0.y * a0.y + a0.z * a0.z + a0.w * a0.w +
                      a1.x * a1.x + a1.y * a1.y + a1.z * a1.z + a1.w * a1.w;
#pragma unroll
            for (int off = 32; off > 0; off >>= 1) s += __shfl_down(s, off);
            if (lane == 0) sq[r] = s;
        }
    }
}

// ---------------- per-row triplet loss ----------------
__global__ __launch_bounds__(64) void loss_kernel(
        const float* __restrict__ E, const float* __restrict__ sq,
        const int* __restrict__ idxp, const int* __restrict__ idxn,
        float* __restrict__ tl) {
    const int r = blockIdx.x;
    const int lane = threadIdx.x;
    const int ip = idxp[r];
    const int in_ = idxn[r];
    const float4* er = (const float4*)(E + (size_t)r * D);
    float dp = 0.f, dn = 0.f;
    float4 a0 = er[lane * 2];
    float4 a1 = er[lane * 2 + 1];
    if (ip >= 0) {
        const float4* ep = (const float4*)(E + (size_t)ip * D);
        float4 b0 = ep[lane * 2];
        float4 b1 = ep[lane * 2 + 1];
        dp = a0.x * b0.x + a0.y * b0.y + a0.z * b0.z + a0.w * b0.w +
             a1.x * b1.x + a1.y * b1.y + a1.z * b1.z + a1.w * b1.w;
    }
    if (in_ >= 0) {
        const float4* en = (const float4*)(E + (size_t)in_ * D);
        float4 b0 = en[lane * 2];
        float4 b1 = en[lane * 2 + 1];
        dn = a0.x * b0.x + a0.y * b0.y + a0.z * b0.z + a0.w * b0.w +
             a1.x * b1.x + a1.y * b1.y + a1.z * b1.z + a1.w * b1.w;
    }
#pragma unroll
    for (int off = 32; off > 0; off >>= 1) {
        dp += __shfl_down(dp, off);
        dn += __shfl_down(dn, off);
    }
    if (lane == 0) {
        const float pd = (ip >= 0) ? fmaxf(sq[r] + sq[ip] - 2.0f * dp, 0.f) : 0.f;
        const float nd = (in_ >= 0) ? fmaxf(sq[r] + sq[in_] - 2.0f * dn, 0.f) : 0.f;
        tl[r] = fmaxf(pd - nd + 1.0f, 0.f);
    }
}

// ---------------- deterministic final reduction ----------------
__global__ __launch_bounds__(256) void finalize_kernel(
        const float* __restrict__ tl, float* __restrict__ out) {
    const int t = threadIdx.x;
    float s = 0.f;
    int c = 0;
    for (int j = t; j < B; j += 256) {
        const float v = tl[j];
        s += v;
        if (v > 1e-16f) c++;
    }
#pragma unroll
    for (int off = 32; off > 0; off >>= 1) {
        s += __shfl_down(s, off);
        c += __shfl_down(c, off);
    }
    __shared__ float ss[4];
    __shared__ int sc[4];
    if ((t & 63) == 0) { ss[t >> 6] = s; sc[t >> 6] = c; }
    __syncthreads();
    if (t == 0) {
#pragma unroll
        for (int k = 1; k < 4; ++k) { s += ss[k]; c += sc[k]; }
        out[0] = (c == 0) ? 0.0f : s * (1.0f / 4096.0f);
    }
}

extern "C" void kernel_launch(void* const* d_in, const int* in_sizes, int n_in,
                              void* d_out, int out_size, void* d_ws,
                              size_t ws_size, hipStream_t stream) {
    const float* E = (const float*)d_in[0];
    const int* labels = (const int*)d_in[1];
    float* out = (float*)d_out;

    char* ws = (char*)d_ws;
    float* sq = (float*)(ws);                 // 16 KB
    int* idxp = (int*)(ws + 16384);           // 16 KB
    int* idxn = (int*)(ws + 32768);           // 16 KB
    float* tl = (float*)(ws + 49152);         // 16 KB

    // Host-side key derivation (matches jax.random.split of key(42),
    // jax_threefry_partitionable=True; verified bit-exact in round 1).
    uint32_t kp0, kp1, kn0, kn1;
    tf2x32(0u, 42u, 0u, 0u, kp0, kp1);
    tf2x32(0u, 42u, 0u, 1u, kn0, kn1);

    fused_select_kernel<<<NB_TOTAL, 256, 0, stream>>>(E, labels, sq, idxp,
                                                      idxn, kp0, kp1, kn0, kn1);
    loss_kernel<<<B, 64, 0, stream>>>(E, sq, idxp, idxn, tl);
    finalize_kernel<<<1, 256, 0, stream>>>(tl, out);
}

// Round 3
// 62.559 us; speedup vs baseline: 1.3140x; 1.0152x over previous
//
#include <hip/hip_runtime.h>
#include <stdint.h>

#define B 4096
#define D 512

// Grid layout of the fused select kernel (all blocks 256 threads):
//   [0, 4096)     : negative-selection, one block per row (16 cols/thread)
//   [4096, 4112)  : positive-selection, thread-per-row via label buckets
//   [4112, 4176)  : sq[r] = ||E[r]||^2, 64 rows per block (16 per wave)
#define NB_NEG 4096
#define NB_POS 16
#define NB_SQ 64
#define NB_TOTAL (NB_NEG + NB_POS + NB_SQ)

__host__ __device__ __forceinline__ uint32_t rotl32(uint32_t x, int d) {
    return (x << d) | (x >> (32 - d));
}

// Threefry-2x32, 20 rounds — bit-exact match of jax._src.prng.threefry2x32.
__host__ __device__ __forceinline__ void tf2x32(uint32_t k0, uint32_t k1,
                                                uint32_t x0, uint32_t x1,
                                                uint32_t& o0, uint32_t& o1) {
    const uint32_t k2 = k0 ^ k1 ^ 0x1BD11BDAu;
#define TF_ROUND(r) { x0 += x1; x1 = rotl32(x1, r); x1 ^= x0; }
    x0 += k0; x1 += k1;
    TF_ROUND(13) TF_ROUND(15) TF_ROUND(26) TF_ROUND(6)
    x0 += k1; x1 += k2 + 1u;
    TF_ROUND(17) TF_ROUND(29) TF_ROUND(16) TF_ROUND(24)
    x0 += k2; x1 += k0 + 2u;
    TF_ROUND(13) TF_ROUND(15) TF_ROUND(26) TF_ROUND(6)
    x0 += k0; x1 += k1 + 3u;
    TF_ROUND(17) TF_ROUND(29) TF_ROUND(16) TF_ROUND(24)
    x0 += k1; x1 += k2 + 4u;
    TF_ROUND(13) TF_ROUND(15) TF_ROUND(26) TF_ROUND(6)
    x0 += k2; x1 += k0 + 5u;
#undef TF_ROUND
    o0 = x0; o1 = x1;
}

// JAX partitionable draw for uint32 element `flat`: counter (0, flat), fold.
__device__ __forceinline__ uint32_t draw32(uint32_t k0, uint32_t k1,
                                           uint32_t flat) {
    uint32_t o0, o1;
    tf2x32(k0, k1, 0u, flat, o0, o1);
    return o0 ^ o1;
}

__device__ __forceinline__ unsigned long long umax64(unsigned long long a,
                                                     unsigned long long b) {
    return a > b ? a : b;
}

// Pack (bestv, bestc) so that u64-max == (larger uniform, then smaller col).
// bestv in [0, 2^23); +1 so pack==0 <=> "no candidate".
__device__ __forceinline__ unsigned long long packbest(int bestv, int bestc) {
    return (bestv < 0)
               ? 0ull
               : ((((unsigned long long)(uint32_t)bestv + 1ull) << 12) |
                  (unsigned long long)(uint32_t)(4095 - bestc));
}

// ---------------- Kernel 0: label buckets (counting sort, 1 block) --------
__global__ __launch_bounds__(256) void bucket_kernel(
        const int* __restrict__ labels, int* __restrict__ bstart,
        int* __restrict__ bcols) {
    __shared__ int hist[256];
    __shared__ int base[256];
    const int t = threadIdx.x;
    hist[t] = 0;
    __syncthreads();
    int lab[16];
#pragma unroll
    for (int j = 0; j < 16; ++j) {
        lab[j] = labels[t + j * 256];
        atomicAdd(&hist[lab[j]], 1);
    }
    __syncthreads();
    if (t == 0) {
        int acc = 0;
        for (int i = 0; i < 256; ++i) { base[i] = acc; acc += hist[i]; }
    }
    __syncthreads();
    bstart[t] = base[t];
    if (t == 255) bstart[256] = base[255] + hist[255];
    hist[t] = 0;
    __syncthreads();
#pragma unroll
    for (int j = 0; j < 16; ++j) {
        const int c = t + j * 256;
        const int l = lab[j];
        const int off = atomicAdd(&hist[l], 1);
        bcols[base[l] + off] = c;
    }
}

// ---------------- Kernel 1: fused neg-select / pos-select / sq ------------
__global__ __launch_bounds__(256) void fused_select_kernel(
        const float* __restrict__ E, const int* __restrict__ labels,
        const int* __restrict__ bstart, const int* __restrict__ bcols,
        float* __restrict__ sq, int* __restrict__ idxp, int* __restrict__ idxn,
        uint32_t kp0, uint32_t kp1, uint32_t kn0, uint32_t kn1) {
    const int bid = blockIdx.x;
    const int t = threadIdx.x;
    const int lane = t & 63;
    const int w = t >> 6;

    if (bid < NB_NEG) {
        // ----- negative selection: row = bid, hash kn for ALL columns -----
        __shared__ int slab[B];
        for (int j = t; j < B / 4; j += 256)
            ((int4*)slab)[j] = ((const int4*)labels)[j];
        __syncthreads();
        const int r = bid;
        const int labr = slab[r];
        const uint32_t rbase = (uint32_t)r << 12;

        // Preload this thread's 16 labels into registers (no LDS traffic
        // inside the hash loop -> 16 independent Threefry chains, pure VALU).
        int labc[16];
#pragma unroll
        for (int j = 0; j < 16; ++j) labc[j] = slab[t + j * 256];

        int bestv = -1, bestc = 0;
#pragma unroll
        for (int j = 0; j < 16; ++j) {
            const int c = t + j * 256;
            const uint32_t bits = draw32(kn0, kn1, rbase + (uint32_t)c);
            const int v = (int)(bits >> 9);
            if ((labc[j] != labr) & (v > bestv)) { bestv = v; bestc = c; }
        }
        unsigned long long best = packbest(bestv, bestc);
#pragma unroll
        for (int off = 32; off > 0; off >>= 1)
            best = umax64(best, __shfl_down(best, off));
        __shared__ unsigned long long red[4];
        if (lane == 0) red[w] = best;
        __syncthreads();
        if (t == 0) {
#pragma unroll
            for (int k = 1; k < 4; ++k) best = umax64(best, red[k]);
            idxn[r] = best ? (int)(4095u - (uint32_t)(best & 0xFFFull)) : -1;
        }
    } else if (bid < NB_NEG + NB_POS) {
        // ----- positive selection: thread-per-row over label bucket -----
        const int r = (bid - NB_NEG) * 256 + t;
        const int lab = labels[r];
        const int s0 = bstart[lab];
        const int s1 = bstart[lab + 1];
        const uint32_t rbase = (uint32_t)r << 12;
        unsigned long long best = 0ull;
        for (int i = s0; i < s1; ++i) {
            const int c = bcols[i];
            if (c == r) continue;
            const uint32_t bits = draw32(kp0, kp1, rbase + (uint32_t)c);
            const unsigned long long pack =
                ((((unsigned long long)(bits >> 9)) + 1ull) << 12) |
                (unsigned long long)(uint32_t)(4095 - c);
            best = umax64(best, pack);
        }
        idxp[r] = best ? (int)(4095u - (uint32_t)(best & 0xFFFull)) : -1;
    } else {
        // ----- sq: 16 rows per wave -----
        const int base = (bid - NB_NEG - NB_POS) * 64 + w * 16;
#pragma unroll 2
        for (int k = 0; k < 16; ++k) {
            const int r = base + k;
            const float4* er = (const float4*)(E + (size_t)r * D);
            float4 a0 = er[lane * 2];
            float4 a1 = er[lane * 2 + 1];
            float s = a0.x * a0.x + a0.y * a0.y + a0.z * a0.z + a0.w * a0.w +
                      a1.x * a1.x + a1.y * a1.y + a1.z * a1.z + a1.w * a1.w;
#pragma unroll
            for (int off = 32; off > 0; off >>= 1) s += __shfl_down(s, off);
            if (lane == 0) sq[r] = s;
        }
    }
}

// ---------------- per-row triplet loss ----------------
__global__ __launch_bounds__(64) void loss_kernel(
        const float* __restrict__ E, const float* __restrict__ sq,
        const int* __restrict__ idxp, const int* __restrict__ idxn,
        float* __restrict__ tl) {
    const int r = blockIdx.x;
    const int lane = threadIdx.x;
    const int ip = idxp[r];
    const int in_ = idxn[r];
    const float4* er = (const float4*)(E + (size_t)r * D);
    float dp = 0.f, dn = 0.f;
    float4 a0 = er[lane * 2];
    float4 a1 = er[lane * 2 + 1];
    if (ip >= 0) {
        const float4* ep = (const float4*)(E + (size_t)ip * D);
        float4 b0 = ep[lane * 2];
        float4 b1 = ep[lane * 2 + 1];
        dp = a0.x * b0.x + a0.y * b0.y + a0.z * b0.z + a0.w * b0.w +
             a1.x * b1.x + a1.y * b1.y + a1.z * b1.z + a1.w * b1.w;
    }
    if (in_ >= 0) {
        const float4* en = (const float4*)(E + (size_t)in_ * D);
        float4 b0 = en[lane * 2];
        float4 b1 = en[lane * 2 + 1];
        dn = a0.x * b0.x + a0.y * b0.y + a0.z * b0.z + a0.w * b0.w +
             a1.x * b1.x + a1.y * b1.y + a1.z * b1.z + a1.w * b1.w;
    }
#pragma unroll
    for (int off = 32; off > 0; off >>= 1) {
        dp += __shfl_down(dp, off);
        dn += __shfl_down(dn, off);
    }
    if (lane == 0) {
        const float pd = (ip >= 0) ? fmaxf(sq[r] + sq[ip] - 2.0f * dp, 0.f) : 0.f;
        const float nd = (in_ >= 0) ? fmaxf(sq[r] + sq[in_] - 2.0f * dn, 0.f) : 0.f;
        tl[r] = fmaxf(pd - nd + 1.0f, 0.f);
    }
}

// ---------------- deterministic final reduction ----------------
__global__ __launch_bounds__(256) void finalize_kernel(
        const float* __restrict__ tl, float* __restrict__ out) {
    const int t = threadIdx.x;
    float s = 0.f;
    int c = 0;
    for (int j = t; j < B; j += 256) {
        const float v = tl[j];
        s += v;
        if (v > 1e-16f) c++;
    }
#pragma unroll
    for (int off = 32; off > 0; off >>= 1) {
        s += __shfl_down(s, off);
        c += __shfl_down(c, off);
    }
    __shared__ float ss[4];
    __shared__ int sc[4];
    if ((t & 63) == 0) { ss[t >> 6] = s; sc[t >> 6] = c; }
    __syncthreads();
    if (t == 0) {
#pragma unroll
        for (int k = 1; k < 4; ++k) { s += ss[k]; c += sc[k]; }
        out[0] = (c == 0) ? 0.0f : s * (1.0f / 4096.0f);
    }
}

extern "C" void kernel_launch(void* const* d_in, const int* in_sizes, int n_in,
                              void* d_out, int out_size, void* d_ws,
                              size_t ws_size, hipStream_t stream) {
    const float* E = (const float*)d_in[0];
    const int* labels = (const int*)d_in[1];
    float* out = (float*)d_out;

    char* ws = (char*)d_ws;
    float* sq = (float*)(ws);                 // 16 KB
    int* idxp = (int*)(ws + 16384);           // 16 KB
    int* idxn = (int*)(ws + 32768);           // 16 KB
    float* tl = (float*)(ws + 49152);         // 16 KB
    int* bstart = (int*)(ws + 65536);         // 4 KB (257 used)
    int* bcols = (int*)(ws + 69632);          // 16 KB

    // Host-side key derivation (matches jax.random.split of key(42),
    // jax_threefry_partitionable=True; verified bit-exact in round 1).
    uint32_t kp0, kp1, kn0, kn1;
    tf2x32(0u, 42u, 0u, 0u, kp0, kp1);
    tf2x32(0u, 42u, 0u, 1u, kn0, kn1);

    bucket_kernel<<<1, 256, 0, stream>>>(labels, bstart, bcols);
    fused_select_kernel<<<NB_TOTAL, 256, 0, stream>>>(
        E, labels, bstart, bcols, sq, idxp, idxn, kp0, kp1, kn0, kn1);
    loss_kernel<<<B, 64, 0, stream>>>(E, sq, idxp, idxn, tl);
    finalize_kernel<<<1, 256, 0, stream>>>(tl, out);
}

// Round 4
// 61.529 us; speedup vs baseline: 1.3360x; 1.0167x over previous
//
#include <hip/hip_runtime.h>
#include <stdint.h>

#define B 4096
#define D 512

// Grid layout of the fused select kernel (all blocks 256 threads):
//   [0, 512)    : negative-selection, 8 rows per block (16 cols/thread/row)
//   [512, 528)  : positive-selection, 256 rows per block via in-block buckets
//   [528, 592)  : sq[r] = ||E[r]||^2, 64 rows per block (16 per wave)
#define NB_NEG 512
#define NB_POS 16
#define NB_SQ 64
#define NB_TOTAL (NB_NEG + NB_POS + NB_SQ)
#define ROWS 8

__host__ __device__ __forceinline__ uint32_t rotl32(uint32_t x, int d) {
    return (x << d) | (x >> (32 - d));
}

// Threefry-2x32, 20 rounds — bit-exact match of jax._src.prng.threefry2x32.
__host__ __device__ __forceinline__ void tf2x32(uint32_t k0, uint32_t k1,
                                                uint32_t x0, uint32_t x1,
                                                uint32_t& o0, uint32_t& o1) {
    const uint32_t k2 = k0 ^ k1 ^ 0x1BD11BDAu;
#define TF_ROUND(r) { x0 += x1; x1 = rotl32(x1, r); x1 ^= x0; }
    x0 += k0; x1 += k1;
    TF_ROUND(13) TF_ROUND(15) TF_ROUND(26) TF_ROUND(6)
    x0 += k1; x1 += k2 + 1u;
    TF_ROUND(17) TF_ROUND(29) TF_ROUND(16) TF_ROUND(24)
    x0 += k2; x1 += k0 + 2u;
    TF_ROUND(13) TF_ROUND(15) TF_ROUND(26) TF_ROUND(6)
    x0 += k0; x1 += k1 + 3u;
    TF_ROUND(17) TF_ROUND(29) TF_ROUND(16) TF_ROUND(24)
    x0 += k1; x1 += k2 + 4u;
    TF_ROUND(13) TF_ROUND(15) TF_ROUND(26) TF_ROUND(6)
    x0 += k2; x1 += k0 + 5u;
#undef TF_ROUND
    o0 = x0; o1 = x1;
}

// JAX partitionable draw for uint32 element `flat`: counter (0, flat), fold.
__device__ __forceinline__ uint32_t draw32(uint32_t k0, uint32_t k1,
                                           uint32_t flat) {
    uint32_t o0, o1;
    tf2x32(k0, k1, 0u, flat, o0, o1);
    return o0 ^ o1;
}

__device__ __forceinline__ unsigned long long umax64(unsigned long long a,
                                                     unsigned long long b) {
    return a > b ? a : b;
}

// Pack (bestv, bestc) so that u64-max == (larger uniform, then smaller col).
// bestv in [0, 2^23); +1 so pack==0 <=> "no candidate".
__device__ __forceinline__ unsigned long long packbest(int bestv, int bestc) {
    return (bestv < 0)
               ? 0ull
               : ((((unsigned long long)(uint32_t)bestv + 1ull) << 12) |
                  (unsigned long long)(uint32_t)(4095 - bestc));
}

// ---------------- fused neg-select / pos-select(+buckets) / sq ------------
__global__ __launch_bounds__(256) void fused_select_kernel(
        const float* __restrict__ E, const int* __restrict__ labels,
        float* __restrict__ sq, int* __restrict__ idxp, int* __restrict__ idxn,
        uint32_t kp0, uint32_t kp1, uint32_t kn0, uint32_t kn1) {
    __shared__ int slab[B];                     // labels (neg + pos)
    __shared__ int bcols[B];                    // pos: bucketed columns
    __shared__ int cnt[256];                    // pos: per-label count
    __shared__ int basex[256];                  // pos: inclusive scan
    __shared__ int fillc[256];                  // pos: fill cursors
    __shared__ unsigned long long red[ROWS][4]; // neg: cross-wave reduce

    const int bid = blockIdx.x;
    const int t = threadIdx.x;
    const int lane = t & 63;
    const int w = t >> 6;

    if (bid < NB_NEG) {
        // ---- negative selection: rows [r0, r0+8), all 4096 columns ----
        for (int j = t; j < B / 4; j += 256)
            ((int4*)slab)[j] = ((const int4*)labels)[j];
        __syncthreads();
        const int r0 = bid * ROWS;
        int labr[ROWS];
#pragma unroll
        for (int rr = 0; rr < ROWS; ++rr) labr[rr] = slab[r0 + rr];
        int bestv[ROWS], bestc[ROWS];
#pragma unroll
        for (int rr = 0; rr < ROWS; ++rr) { bestv[rr] = -1; bestc[rr] = 0; }
        const uint32_t base0 = (uint32_t)r0 << 12;
        for (int j = 0; j < 16; ++j) {
            const int c = t + j * 256;
            const int labc = slab[c];
            const uint32_t f0 = base0 + (uint32_t)c;
#pragma unroll
            for (int rr = 0; rr < ROWS; ++rr) {
                const uint32_t bits =
                    draw32(kn0, kn1, f0 + ((uint32_t)rr << 12));
                const int v = (int)(bits >> 9);
                if ((labc != labr[rr]) & (v > bestv[rr])) {
                    bestv[rr] = v; bestc[rr] = c;
                }
            }
        }
#pragma unroll
        for (int rr = 0; rr < ROWS; ++rr) {
            unsigned long long best = packbest(bestv[rr], bestc[rr]);
#pragma unroll
            for (int off = 32; off > 0; off >>= 1)
                best = umax64(best, __shfl_down(best, off));
            if (lane == 0) red[rr][w] = best;
        }
        __syncthreads();
        if (t < ROWS) {
            unsigned long long best = red[t][0];
#pragma unroll
            for (int k = 1; k < 4; ++k) best = umax64(best, red[t][k]);
            idxn[r0 + t] = best ? (int)(4095u - (uint32_t)(best & 0xFFFull))
                                : -1;
        }
    } else if (bid < NB_NEG + NB_POS) {
        // ---- positive selection: build label buckets in-block, then ----
        // ---- thread-per-row over this row's bucket.                 ----
        for (int j = t; j < B / 4; j += 256)
            ((int4*)slab)[j] = ((const int4*)labels)[j];
        cnt[t] = 0;
        fillc[t] = 0;
        __syncthreads();
        int lab[16];
#pragma unroll
        for (int j = 0; j < 16; ++j) {
            lab[j] = slab[t + j * 256];
            atomicAdd(&cnt[lab[j]], 1);
        }
        __syncthreads();
        // Hillis-Steele inclusive scan of cnt -> basex
        basex[t] = cnt[t];
        __syncthreads();
        for (int off = 1; off < 256; off <<= 1) {
            const int u = (t >= off) ? basex[t - off] : 0;
            __syncthreads();
            basex[t] += u;
            __syncthreads();
        }
        // fill buckets (order within bucket irrelevant: packed-u64 max)
#pragma unroll
        for (int j = 0; j < 16; ++j) {
            const int c = t + j * 256;
            const int l = lab[j];
            const int off = atomicAdd(&fillc[l], 1);
            bcols[basex[l] - cnt[l] + off] = c;
        }
        __syncthreads();
        const int r = (bid - NB_NEG) * 256 + t;
        const int myl = slab[r];
        const int s1 = basex[myl];
        const int s0 = s1 - cnt[myl];
        const uint32_t rbase = (uint32_t)r << 12;
        unsigned long long best = 0ull;
        for (int i = s0; i < s1; ++i) {
            const int c = bcols[i];
            if (c == r) continue;
            const uint32_t bits = draw32(kp0, kp1, rbase + (uint32_t)c);
            const unsigned long long pack =
                ((((unsigned long long)(bits >> 9)) + 1ull) << 12) |
                (unsigned long long)(uint32_t)(4095 - c);
            best = umax64(best, pack);
        }
        idxp[r] = best ? (int)(4095u - (uint32_t)(best & 0xFFFull)) : -1;
    } else {
        // ---- sq: 16 rows per wave ----
        const int base = (bid - NB_NEG - NB_POS) * 64 + w * 16;
#pragma unroll 2
        for (int k = 0; k < 16; ++k) {
            const int r = base + k;
            const float4* er = (const float4*)(E + (size_t)r * D);
            float4 a0 = er[lane * 2];
            float4 a1 = er[lane * 2 + 1];
            float s = a0.x * a0.x + a0.y * a0.y + a0.z * a0.z + a0.w * a0.w +
                      a1.x * a1.x + a1.y * a1.y + a1.z * a1.z + a1.w * a1.w;
#pragma unroll
            for (int off = 32; off > 0; off >>= 1) s += __shfl_down(s, off);
            if (lane == 0) sq[r] = s;
        }
    }
}

// ---------------- per-row triplet loss (4 rows per block) ----------------
__global__ __launch_bounds__(256) void loss_kernel(
        const float* __restrict__ E, const float* __restrict__ sq,
        const int* __restrict__ idxp, const int* __restrict__ idxn,
        float* __restrict__ tl) {
    const int lane = threadIdx.x & 63;
    const int w = threadIdx.x >> 6;
    const int r = blockIdx.x * 4 + w;
    const int ip = idxp[r];
    const int in_ = idxn[r];
    const float4* er = (const float4*)(E + (size_t)r * D);
    float dp = 0.f, dn = 0.f;
    float4 a0 = er[lane * 2];
    float4 a1 = er[lane * 2 + 1];
    if (ip >= 0) {
        const float4* ep = (const float4*)(E + (size_t)ip * D);
        float4 b0 = ep[lane * 2];
        float4 b1 = ep[lane * 2 + 1];
        dp = a0.x * b0.x + a0.y * b0.y + a0.z * b0.z + a0.w * b0.w +
             a1.x * b1.x + a1.y * b1.y + a1.z * b1.z + a1.w * b1.w;
    }
    if (in_ >= 0) {
        const float4* en = (const float4*)(E + (size_t)in_ * D);
        float4 b0 = en[lane * 2];
        float4 b1 = en[lane * 2 + 1];
        dn = a0.x * b0.x + a0.y * b0.y + a0.z * b0.z + a0.w * b0.w +
             a1.x * b1.x + a1.y * b1.y + a1.z * b1.z + a1.w * b1.w;
    }
#pragma unroll
    for (int off = 32; off > 0; off >>= 1) {
        dp += __shfl_down(dp, off);
        dn += __shfl_down(dn, off);
    }
    if (lane == 0) {
        const float pd = (ip >= 0) ? fmaxf(sq[r] + sq[ip] - 2.0f * dp, 0.f) : 0.f;
        const float nd = (in_ >= 0) ? fmaxf(sq[r] + sq[in_] - 2.0f * dn, 0.f) : 0.f;
        tl[r] = fmaxf(pd - nd + 1.0f, 0.f);
    }
}

// ---------------- deterministic final reduction ----------------
__global__ __launch_bounds__(256) void finalize_kernel(
        const float* __restrict__ tl, float* __restrict__ out) {
    const int t = threadIdx.x;
    float s = 0.f;
    int c = 0;
    for (int j = t; j < B; j += 256) {
        const float v = tl[j];
        s += v;
        if (v > 1e-16f) c++;
    }
#pragma unroll
    for (int off = 32; off > 0; off >>= 1) {
        s += __shfl_down(s, off);
        c += __shfl_down(c, off);
    }
    __shared__ float ss[4];
    __shared__ int sc[4];
    if ((t & 63) == 0) { ss[t >> 6] = s; sc[t >> 6] = c; }
    __syncthreads();
    if (t == 0) {
#pragma unroll
        for (int k = 1; k < 4; ++k) { s += ss[k]; c += sc[k]; }
        out[0] = (c == 0) ? 0.0f : s * (1.0f / 4096.0f);
    }
}

extern "C" void kernel_launch(void* const* d_in, const int* in_sizes, int n_in,
                              void* d_out, int out_size, void* d_ws,
                              size_t ws_size, hipStream_t stream) {
    const float* E = (const float*)d_in[0];
    const int* labels = (const int*)d_in[1];
    float* out = (float*)d_out;

    char* ws = (char*)d_ws;
    float* sq = (float*)(ws);                 // 16 KB
    int* idxp = (int*)(ws + 16384);           // 16 KB
    int* idxn = (int*)(ws + 32768);           // 16 KB
    float* tl = (float*)(ws + 49152);         // 16 KB

    // Host-side key derivation (matches jax.random.split of key(42),
    // jax_threefry_partitionable=True; verified bit-exact in round 1).
    uint32_t kp0, kp1, kn0, kn1;
    tf2x32(0u, 42u, 0u, 0u, kp0, kp1);
    tf2x32(0u, 42u, 0u, 1u, kn0, kn1);

    fused_select_kernel<<<NB_TOTAL, 256, 0, stream>>>(E, labels, sq, idxp,
                                                      idxn, kp0, kp1, kn0, kn1);
    loss_kernel<<<B / 4, 256, 0, stream>>>(E, sq, idxp, idxn, tl);
    finalize_kernel<<<1, 256, 0, stream>>>(tl, out);
}